// Round 4
// baseline (977.461 us; speedup 1.0000x reference)
//
#include <hip/hip_runtime.h>
#include <cstdint>
#include <cstddef>

#define EPS_F 1e-6f

// ---------- bf16 helpers ----------
__device__ inline unsigned short f2bf(float f) {
    union { float f; unsigned u; } v; v.f = f;
    unsigned r = v.u + 0x7fffu + ((v.u >> 16) & 1u);   // RNE
    return (unsigned short)(r >> 16);
}
__device__ inline float bf2f(unsigned u16) {           // low 16 bits used
    union { unsigned u; float f; } v; v.u = u16 << 16; return v.f;
}

typedef __attribute__((ext_vector_type(8))) __bf16 bf16x8;
typedef __attribute__((ext_vector_type(8))) short short8;
typedef __attribute__((ext_vector_type(8))) unsigned short ushort8;
typedef __attribute__((ext_vector_type(4))) float floatx4;

__device__ inline void async_load16(const void* g, void* l) {
    __builtin_amdgcn_global_load_lds((const __attribute__((address_space(1))) void*)g,
                                     (__attribute__((address_space(3))) void*)l,
                                     16, 0, 0);
}

// ---------- cast fp32 -> bf16, 8 elems/thread (16B store) ----------
__global__ void cast_x_kernel(const float* __restrict__ in, unsigned short* __restrict__ out, int n8) {
    int i = blockIdx.x * blockDim.x + threadIdx.x;
    if (i < n8) {
        float4 a = ((const float4*)in)[2 * i];
        float4 b = ((const float4*)in)[2 * i + 1];
        short8 o;
        o[0] = (short)f2bf(a.x); o[1] = (short)f2bf(a.y);
        o[2] = (short)f2bf(a.z); o[3] = (short)f2bf(a.w);
        o[4] = (short)f2bf(b.x); o[5] = (short)f2bf(b.y);
        o[6] = (short)f2bf(b.z); o[7] = (short)f2bf(b.w);
        ((short8*)out)[i] = o;
    }
}

// ---------- transpose + cast 4 weights in one dispatch (blockIdx.z selects) ----------
__global__ void transpose_cast_kernel(const float* __restrict__ W0, const float* __restrict__ W1,
                                      const float* __restrict__ W2, const float* __restrict__ W3,
                                      unsigned short* __restrict__ WtBase, int n) {
    const float* W = (blockIdx.z == 0) ? W0 : (blockIdx.z == 1) ? W1 : (blockIdx.z == 2) ? W2 : W3;
    unsigned short* Wt = WtBase + (size_t)blockIdx.z * n * n;
    __shared__ float tile[32][33];
    int bx = blockIdx.x * 32;
    int by = blockIdx.y * 32;
    int tx = threadIdx.x;        // 0..31
    int ty = threadIdx.y;        // 0..7
    #pragma unroll
    for (int i = 0; i < 32; i += 8)
        tile[ty + i][tx] = W[(size_t)(by + ty + i) * n + bx + tx];
    __syncthreads();
    #pragma unroll
    for (int i = 0; i < 32; i += 8)
        Wt[(size_t)(bx + ty + i) * n + by + tx] = f2bf(tile[tx][ty + i]);
}

// ---------- bf16 MFMA GEMM core, 128x128 / BK=64 (R0 proven structure) + T1 swizzle --
// FINAL=0: fused QKV. Bt is (3*D x K) = [WqT;WkT;WvT]; epilogue per n-block:
//   mat 0: q=elu(v+bq)+1 ; mat 1: k=(elu(v+bk)+1)*mask ; mat 2: v=(v+bv)*mask ; bf16 out
// FINAL=1: out = A*WoT^T + bo, fp32 out
#define BMT 128
#define BNT 128
#define BKT 64
#define DMODEL 2048

template<int FINAL>
__global__ __launch_bounds__(256, 2)
void gemm_kernel(const unsigned short* __restrict__ A,
                 const unsigned short* __restrict__ Bt,
                 const float* __restrict__ b0, const float* __restrict__ b1,
                 const float* __restrict__ b2,
                 const float* __restrict__ mask,
                 unsigned short* __restrict__ qo, unsigned short* __restrict__ ko,
                 unsigned short* __restrict__ vo,
                 float* __restrict__ Cf,
                 int M, int K) {
    // 128 rows x 64 cols bf16 = 16KB each; rows are 8 chunks of 16B.
    // LDS slot (r, c) holds global chunk (c ^ (r&7))  -> breaks power-of-2 bank stride.
    __shared__ __align__(16) unsigned short As[BMT * BKT];
    __shared__ __align__(16) unsigned short Bs[BNT * BKT];

    const int tid  = threadIdx.x;
    const int wave = tid >> 6;
    const int lane = tid & 63;

    // T1: XCD-aware swizzle. nwg % 8 == 0 for both grids (6144 / 2048) -> bijective.
    // Each XCD gets a contiguous run of n-panels: B panel stays L2-hot, A streams L3.
    const int nwg = (int)(gridDim.x * gridDim.y);
    const int bid = (int)(blockIdx.y * gridDim.x + blockIdx.x);
    const int cpx = nwg >> 3;
    const int swz = (bid & 7) * cpx + (bid >> 3);
    const int bm  = swz % (int)gridDim.x;
    const int bn  = swz / (int)gridDim.x;

    const int m0    = bm * BMT;
    const int nglob = bn * BNT;
    int mat, n0;
    const float* bias;
    unsigned short* Cb = nullptr;
    if (FINAL) {
        mat = 0; n0 = nglob; bias = b0;
    } else {
        mat  = nglob >> 11;            // /DMODEL
        n0   = nglob & (DMODEL - 1);
        bias = (mat == 0) ? b0 : (mat == 1) ? b1 : b2;
        Cb   = (mat == 0) ? qo : (mat == 1) ? ko : vo;
    }
    const int wm = (wave >> 1) * 64;
    const int wn = (wave & 1) * 64;
    const int quad  = lane >> 4;
    const int row16 = lane & 15;

    floatx4 acc[4][4] = {};

    // staging geometry: per matrix 1024 chunks = 128 rows x 8; 4 batches of 64 per wave
    const int srow_lo = lane >> 3;                 // 0..7 within batch
    const int schunk  = lane & 7;

    for (int k0 = 0; k0 < K; k0 += BKT) {
        #pragma unroll
        for (int i = 0; i < 4; i++) {
            int slot_base = wave * 256 + i * 64;          // wave-uniform LDS base (x16B)
            int r  = wave * 32 + i * 8 + srow_lo;         // tile row for this lane
            int cg = schunk ^ (r & 7);                    // global chunk feeding this slot
            const unsigned short* ga = A  + (size_t)(m0 + r) * K + k0 + cg * 8;
            const unsigned short* gb = Bt + (size_t)(nglob + r) * K + k0 + cg * 8;
            async_load16(ga, As + (size_t)slot_base * 8);
            async_load16(gb, Bs + (size_t)slot_base * 8);
        }
        __syncthreads();

        #pragma unroll
        for (int kk = 0; kk < 2; kk++) {                  // two 32-wide k-windows
            bf16x8 af[4], bfr[4];
            #pragma unroll
            for (int t = 0; t < 4; t++) {
                int ra = wm + t * 16 + row16;
                int ca = (kk * 4 + quad) ^ (ra & 7);
                af[t]  = __builtin_bit_cast(bf16x8, *(const short8*)(As + (size_t)ra * 64 + ca * 8));
                int rb = wn + t * 16 + row16;
                int cb = (kk * 4 + quad) ^ (rb & 7);
                bfr[t] = __builtin_bit_cast(bf16x8, *(const short8*)(Bs + (size_t)rb * 64 + cb * 8));
            }
            #pragma unroll
            for (int i = 0; i < 4; i++)
                #pragma unroll
                for (int j = 0; j < 4; j++)
                    acc[i][j] = __builtin_amdgcn_mfma_f32_16x16x32_bf16(af[i], bfr[j], acc[i][j], 0, 0, 0);
        }
        __syncthreads();
    }

    // epilogue: D row = wm+i*16+quad*4+r, col = wn+j*16+row16
    float bcache[4];
    #pragma unroll
    for (int j = 0; j < 4; j++) bcache[j] = bias[n0 + wn + j * 16 + row16];
    #pragma unroll
    for (int i = 0; i < 4; i++) {
        #pragma unroll
        for (int r = 0; r < 4; r++) {
            int row = m0 + wm + i * 16 + quad * 4 + r;
            float mr = 1.0f;
            if (!FINAL && mat >= 1) mr = mask[row];
            #pragma unroll
            for (int j = 0; j < 4; j++) {
                int col = n0 + wn + j * 16 + row16;
                float v = acc[i][j][r] + bcache[j];
                if (FINAL) {
                    Cf[(size_t)row * DMODEL + col] = v;
                } else {
                    if (mat <= 1) v = (v > 0.f) ? (v + 1.f) : __expf(v);  // elu+1
                    v *= mr;
                    Cb[(size_t)row * DMODEL + col] = f2bf(v);
                }
            }
        }
    }
}

// ---------- linear-attention scan (elementwise kv), chunked 3-pass ----------
#define SL    4096
#define SD    2048
#define SH    16
#define CHUNK 64
#define NCH   64   // SL / CHUNK

// Pass A: per-(b,h,chunk) partial sums. lane = tg*16+dg: 4 t-rows in flight,
// 16B/lane loads; summation is order-free so cross-lane combine at the end.
__global__ void scan_partial_kernel(const unsigned short* __restrict__ k,
                                    const unsigned short* __restrict__ v,
                                    float* __restrict__ sumK, float* __restrict__ sumKV) {
    int blk = blockIdx.x;
    int c = blk & (NCH - 1), bh = blk >> 6;
    int b = bh >> 4, h = bh & (SH - 1);
    int lane = threadIdx.x;
    int tg = lane >> 4, dg = lane & 15;
    size_t base = ((size_t)(b * SL + c * CHUNK + tg)) * SD + h * 128 + dg * 8;
    float sk[8] = {0.f, 0.f, 0.f, 0.f, 0.f, 0.f, 0.f, 0.f};
    float skv[8] = {0.f, 0.f, 0.f, 0.f, 0.f, 0.f, 0.f, 0.f};
    for (int it = 0; it < CHUNK / 4; it++) {
        ushort8 kw = *(const ushort8*)(k + base);
        ushort8 vw = *(const ushort8*)(v + base);
        #pragma unroll
        for (int j = 0; j < 8; j++) {
            float kf = bf2f(kw[j]);
            float vf = bf2f(vw[j]);
            sk[j] += kf; skv[j] += kf * vf;
        }
        base += (size_t)4 * SD;
    }
    #pragma unroll
    for (int j = 0; j < 8; j++) {
        sk[j]  += __shfl_xor(sk[j], 16);  sk[j]  += __shfl_xor(sk[j], 32);
        skv[j] += __shfl_xor(skv[j], 16); skv[j] += __shfl_xor(skv[j], 32);
    }
    if (tg == 0) {
        size_t o = ((size_t)bh * NCH + c) * 128 + dg * 8;
        *(float4*)(sumK  + o)     = make_float4(sk[0], sk[1], sk[2], sk[3]);
        *(float4*)(sumK  + o + 4) = make_float4(sk[4], sk[5], sk[6], sk[7]);
        *(float4*)(sumKV + o)     = make_float4(skv[0], skv[1], skv[2], skv[3]);
        *(float4*)(sumKV + o + 4) = make_float4(skv[4], skv[5], skv[6], skv[7]);
    }
}

// Pass B: exclusive scan of chunk sums along chunk axis, per (b,h,d).
// Register-batched: 32 independent coalesced loads in flight, then scan+store.
// (Old version: 64 blocks, 64-deep dependent serial loop -> latency-bound.)
__global__ __launch_bounds__(64)
void scan_offsets_kernel(const float* __restrict__ sumK, const float* __restrict__ sumKV,
                         float* __restrict__ offK, float* __restrict__ offKV) {
    int blk = blockIdx.x;            // 0..127 = bh*2 + dh
    int bh  = blk >> 1;
    int d   = (blk & 1) * 64 + threadIdx.x;
    float aK = 0.f, aKV = 0.f;
    #pragma unroll 1
    for (int h = 0; h < 2; h++) {
        float vK[32], vKV[32];
        #pragma unroll
        for (int c2 = 0; c2 < 32; c2++) {
            size_t o = ((size_t)bh * NCH + h * 32 + c2) * 128 + d;
            vK[c2] = sumK[o]; vKV[c2] = sumKV[o];
        }
        #pragma unroll
        for (int c2 = 0; c2 < 32; c2++) {
            size_t o = ((size_t)bh * NCH + h * 32 + c2) * 128 + d;
            offK[o]  = aK;  aK  += vK[c2];
            offKV[o] = aKV; aKV += vKV[c2];
        }
    }
}

// Pass C: within-chunk sequential scan, 8-timestep batches: 24 loads in flight,
// 8 interleaved shuffle-reduction trees amortize the 6-step latency.
__global__ void scan_final_kernel(const unsigned short* __restrict__ q,
                                  const unsigned short* __restrict__ k,
                                  const unsigned short* __restrict__ v,
                                  const float* __restrict__ offK, const float* __restrict__ offKV,
                                  const float* __restrict__ mask,
                                  unsigned short* __restrict__ out) {
    int blk = blockIdx.x;
    int c = blk & (NCH - 1), bh = blk >> 6;
    int b = bh >> 4, h = bh & (SH - 1);
    int lane = threadIdx.x;
    size_t ob = ((size_t)bh * NCH + c) * 128 + 2 * lane;
    float2 kcv = *(const float2*)(offK  + ob);
    float2 kvv = *(const float2*)(offKV + ob);
    float kc0 = kcv.x, kc1 = kcv.y, kv0 = kvv.x, kv1 = kvv.y;
    size_t base = ((size_t)(b * SL + c * CHUNK)) * SD + h * 128 + 2 * lane;
    const float* mrow = mask + (size_t)b * SL + c * CHUNK;
    for (int s = 0; s < CHUNK / 8; s++) {
        unsigned kw[8], vw[8], qw[8];
        #pragma unroll
        for (int u = 0; u < 8; u++) {
            size_t a = base + (size_t)u * SD;
            kw[u] = *(const unsigned*)(k + a);
            vw[u] = *(const unsigned*)(v + a);
            qw[u] = *(const unsigned*)(q + a);
        }
        float p[8], n0[8], n1[8];
        #pragma unroll
        for (int u = 0; u < 8; u++) {
            float kk0 = bf2f(kw[u] & 0xffff), kk1 = bf2f(kw[u] >> 16);
            float vv0 = bf2f(vw[u] & 0xffff), vv1 = bf2f(vw[u] >> 16);
            float qq0 = bf2f(qw[u] & 0xffff), qq1 = bf2f(qw[u] >> 16);
            kc0 += kk0; kc1 += kk1;
            kv0 += kk0 * vv0; kv1 += kk1 * vv1;
            p[u]  = qq0 * kc0 + qq1 * kc1;
            n0[u] = qq0 * kv0; n1[u] = qq1 * kv1;
        }
        #pragma unroll
        for (int off = 32; off > 0; off >>= 1) {
            #pragma unroll
            for (int u = 0; u < 8; u++) p[u] += __shfl_xor(p[u], off);
        }
        #pragma unroll
        for (int u = 0; u < 8; u++) {
            float z = (p[u] + EPS_F) * mrow[s * 8 + u];
            float inv = 1.0f / z;
            unsigned o0 = f2bf(n0[u] * inv);
            unsigned o1 = f2bf(n1[u] * inv);
            *(unsigned*)(out + base + (size_t)u * SD) = o0 | (o1 << 16);
        }
        base += (size_t)8 * SD;
    }
}

// ---------- launcher ----------
extern "C" void kernel_launch(void* const* d_in, const int* in_sizes, int n_in,
                              void* d_out, int out_size, void* d_ws, size_t ws_size,
                              hipStream_t stream) {
    const float* x  = (const float*)d_in[0];
    const float* am = (const float*)d_in[1];
    const float* Wq = (const float*)d_in[2];
    const float* bq = (const float*)d_in[3];
    const float* Wk = (const float*)d_in[4];
    const float* bk = (const float*)d_in[5];
    const float* Wv = (const float*)d_in[6];
    const float* bv = (const float*)d_in[7];
    const float* Wo = (const float*)d_in[8];
    const float* bo = (const float*)d_in[9];
    float* out = (float*)d_out;

    const int Bb = 4, L = 4096, D = 2048;
    const int M = Bb * L;                       // 16384
    const size_t MD = (size_t)M * D;            // 33,554,432

    // workspace carve-up (~310 MB). attn aliases xb (xb dead after QKV GEMM).
    char* w = (char*)d_ws;
    unsigned short* xb    = (unsigned short*)w; w += MD * 2;
    unsigned short* qb    = (unsigned short*)w; w += MD * 2;
    unsigned short* kb    = (unsigned short*)w; w += MD * 2;
    unsigned short* vb    = (unsigned short*)w; w += MD * 2;
    unsigned short* WT    = (unsigned short*)w; w += (size_t)4 * D * D * 2; // [WqT;WkT;WvT;WoT]
    float* sumK  = (float*)w; w += (size_t)64 * NCH * 128 * 4;
    float* sumKV = (float*)w; w += (size_t)64 * NCH * 128 * 4;
    float* offK  = (float*)w; w += (size_t)64 * NCH * 128 * 4;
    float* offKV = (float*)w; w += (size_t)64 * NCH * 128 * 4;
    unsigned short* attnb = xb;                 // alias

    // 1) casts / transposes
    int n8 = (int)(MD / 8);
    cast_x_kernel<<<(n8 + 255) / 256, 256, 0, stream>>>(x, xb, n8);
    dim3 tb(32, 8);
    dim3 tg(D / 32, D / 32, 4);
    transpose_cast_kernel<<<tg, tb, 0, stream>>>(Wq, Wk, Wv, Wo, WT, D);

    // 2) fused QKV projection (N = 3*D), epilogues fused. grid 128x48 = 6144 (%8==0)
    dim3 gq(M / BMT, 3 * D / BNT);
    gemm_kernel<0><<<gq, 256, 0, stream>>>(xb, WT, bq, bk, bv, am, qb, kb, vb, nullptr, M, D);

    // 3) chunked linear-attention scan
    scan_partial_kernel<<<64 * NCH, 64, 0, stream>>>(kb, vb, sumK, sumKV);
    scan_offsets_kernel<<<128, 64, 0, stream>>>(sumK, sumKV, offK, offKV);
    scan_final_kernel<<<64 * NCH, 64, 0, stream>>>(qb, kb, vb, offK, offKV, am, attnb);

    // 4) output projection -> fp32 d_out. grid 128x16 = 2048 (%8==0)
    dim3 go(M / BMT, D / BNT);
    gemm_kernel<1><<<go, 256, 0, stream>>>(attnb, WT + (size_t)3 * D * D, bo, nullptr, nullptr,
                                           nullptr, nullptr, nullptr, nullptr, out, M, D);
}

// Round 5
// 896.162 us; speedup vs baseline: 1.0907x; 1.0907x over previous
//
#include <hip/hip_runtime.h>
#include <cstdint>
#include <cstddef>

#define EPS_F 1e-6f

// ---------- bf16 helpers ----------
__device__ inline unsigned short f2bf(float f) {
    union { float f; unsigned u; } v; v.f = f;
    unsigned r = v.u + 0x7fffu + ((v.u >> 16) & 1u);   // RNE
    return (unsigned short)(r >> 16);
}
__device__ inline float bf2f(unsigned u16) {           // low 16 bits used
    union { unsigned u; float f; } v; v.u = u16 << 16; return v.f;
}

typedef __attribute__((ext_vector_type(8))) __bf16 bf16x8;
typedef __attribute__((ext_vector_type(8))) short short8;
typedef __attribute__((ext_vector_type(8))) unsigned short ushort8;
typedef __attribute__((ext_vector_type(4))) float floatx4;
typedef __attribute__((ext_vector_type(4))) unsigned uintx4;

__device__ inline void async_load16(const void* g, void* l) {
    __builtin_amdgcn_global_load_lds((const __attribute__((address_space(1))) void*)g,
                                     (__attribute__((address_space(3))) void*)l,
                                     16, 0, 0);
}

#define LDS_OFF(p) ((unsigned)(unsigned long long)(const __attribute__((address_space(3))) void*)(p))

// ---------- cast fp32 -> bf16, 8 elems/thread (16B store) ----------
__global__ void cast_x_kernel(const float* __restrict__ in, unsigned short* __restrict__ out, int n8) {
    int i = blockIdx.x * blockDim.x + threadIdx.x;
    if (i < n8) {
        float4 a = ((const float4*)in)[2 * i];
        float4 b = ((const float4*)in)[2 * i + 1];
        short8 o;
        o[0] = (short)f2bf(a.x); o[1] = (short)f2bf(a.y);
        o[2] = (short)f2bf(a.z); o[3] = (short)f2bf(a.w);
        o[4] = (short)f2bf(b.x); o[5] = (short)f2bf(b.y);
        o[6] = (short)f2bf(b.z); o[7] = (short)f2bf(b.w);
        ((short8*)out)[i] = o;
    }
}

// ---------- transpose + cast 4 weights in one dispatch (blockIdx.z selects) ----------
__global__ void transpose_cast_kernel(const float* __restrict__ W0, const float* __restrict__ W1,
                                      const float* __restrict__ W2, const float* __restrict__ W3,
                                      unsigned short* __restrict__ WtBase, int n) {
    const float* W = (blockIdx.z == 0) ? W0 : (blockIdx.z == 1) ? W1 : (blockIdx.z == 2) ? W2 : W3;
    unsigned short* Wt = WtBase + (size_t)blockIdx.z * n * n;
    __shared__ float tile[32][33];
    int bx = blockIdx.x * 32;
    int by = blockIdx.y * 32;
    int tx = threadIdx.x;        // 0..31
    int ty = threadIdx.y;        // 0..7
    #pragma unroll
    for (int i = 0; i < 32; i += 8)
        tile[ty + i][tx] = W[(size_t)(by + ty + i) * n + bx + tx];
    __syncthreads();
    #pragma unroll
    for (int i = 0; i < 32; i += 8)
        Wt[(size_t)(bx + ty + i) * n + by + tx] = f2bf(tile[tx][ty + i]);
}

// ---------- QKV GEMM: 128x128 / BK=64, natural block order (R0-proven, 417us) ------
// Bt is (3*D x K) = [WqT;WkT;WvT]; epilogue per n-block:
//   mat 0: q=elu(v+bq)+1 ; mat 1: k=(elu(v+bk)+1)*mask ; mat 2: v=(v+bv)*mask ; bf16 out
#define BMT 128
#define BNT 128
#define BKT 64
#define DMODEL 2048

__global__ __launch_bounds__(256, 2)
void gemm_qkv(const unsigned short* __restrict__ A,
              const unsigned short* __restrict__ Bt,
              const float* __restrict__ b0, const float* __restrict__ b1,
              const float* __restrict__ b2,
              const float* __restrict__ mask,
              unsigned short* __restrict__ qo, unsigned short* __restrict__ ko,
              unsigned short* __restrict__ vo,
              int M, int K) {
    // 128 rows x 64 cols bf16 = 16KB each; rows are 8 chunks of 16B.
    // LDS slot (r, c) holds global chunk (c ^ (r&7))  -> breaks power-of-2 bank stride.
    __shared__ __align__(16) unsigned short As[BMT * BKT];
    __shared__ __align__(16) unsigned short Bs[BNT * BKT];

    const int tid  = threadIdx.x;
    const int wave = tid >> 6;
    const int lane = tid & 63;
    const int m0    = blockIdx.x * BMT;      // natural order: m-fast; concurrent set
    const int nglob = blockIdx.y * BNT;      // shares few n-panels + all of A via L3
    const int mat  = nglob >> 11;            // /DMODEL
    const int n0   = nglob & (DMODEL - 1);
    const float* bias = (mat == 0) ? b0 : (mat == 1) ? b1 : b2;
    unsigned short* Cb = (mat == 0) ? qo : (mat == 1) ? ko : vo;

    const int wm = (wave >> 1) * 64;
    const int wn = (wave & 1) * 64;
    const int quad  = lane >> 4;
    const int row16 = lane & 15;

    floatx4 acc[4][4] = {};

    // staging geometry: per matrix 1024 chunks = 128 rows x 8; 4 batches of 64 per wave
    const int srow_lo = lane >> 3;                 // 0..7 within batch
    const int schunk  = lane & 7;

    for (int k0 = 0; k0 < K; k0 += BKT) {
        #pragma unroll
        for (int i = 0; i < 4; i++) {
            int slot_base = wave * 256 + i * 64;          // wave-uniform LDS base (x16B)
            int r  = wave * 32 + i * 8 + srow_lo;         // tile row for this lane
            int cg = schunk ^ (r & 7);                    // global chunk feeding this slot
            const unsigned short* ga = A  + (size_t)(m0 + r) * K + k0 + cg * 8;
            const unsigned short* gb = Bt + (size_t)(nglob + r) * K + k0 + cg * 8;
            async_load16(ga, As + (size_t)slot_base * 8);
            async_load16(gb, Bs + (size_t)slot_base * 8);
        }
        __syncthreads();

        #pragma unroll
        for (int kk = 0; kk < 2; kk++) {                  // two 32-wide k-windows
            bf16x8 af[4], bfr[4];
            #pragma unroll
            for (int t = 0; t < 4; t++) {
                int ra = wm + t * 16 + row16;
                int ca = (kk * 4 + quad) ^ (ra & 7);
                af[t]  = __builtin_bit_cast(bf16x8, *(const short8*)(As + (size_t)ra * 64 + ca * 8));
                int rb = wn + t * 16 + row16;
                int cb = (kk * 4 + quad) ^ (rb & 7);
                bfr[t] = __builtin_bit_cast(bf16x8, *(const short8*)(Bs + (size_t)rb * 64 + cb * 8));
            }
            #pragma unroll
            for (int i = 0; i < 4; i++)
                #pragma unroll
                for (int j = 0; j < 4; j++)
                    acc[i][j] = __builtin_amdgcn_mfma_f32_16x16x32_bf16(af[i], bfr[j], acc[i][j], 0, 0, 0);
        }
        __syncthreads();
    }

    // epilogue: D row = wm+i*16+quad*4+r, col = wn+j*16+row16
    float bcache[4];
    #pragma unroll
    for (int j = 0; j < 4; j++) bcache[j] = bias[n0 + wn + j * 16 + row16];
    #pragma unroll
    for (int i = 0; i < 4; i++) {
        #pragma unroll
        for (int r = 0; r < 4; r++) {
            int row = m0 + wm + i * 16 + quad * 4 + r;
            float mr = (mat >= 1) ? mask[row] : 1.0f;
            #pragma unroll
            for (int j = 0; j < 4; j++) {
                int col = n0 + wn + j * 16 + row16;
                float v = acc[i][j][r] + bcache[j];
                if (mat <= 1) v = (v > 0.f) ? (v + 1.f) : __expf(v);  // elu+1
                v *= mr;
                Cb[(size_t)row * DMODEL + col] = f2bf(v);
            }
        }
    }
}

// ---------- Final GEMM: 256x256 / BK=32 ring-4 pipelined (R2-proven for N=2048) ----
#define FBK 32
#define FSLOT_ELEMS (256 * FBK)   // 8192 bf16 = 16 KB per slot per matrix
#define FSLOT_BYTES 16384

#define DSR(dst, base, OFF) \
    asm volatile("ds_read_b128 %0, %1 offset:" OFF : "=v"(dst) : "v"(base) : "memory")
#define READ_A0(f, base) { DSR(f[0], base, "0");    DSR(f[1], base, "1024"); \
                           DSR(f[2], base, "2048"); DSR(f[3], base, "3072"); }
#define READ_A1(f, base) { DSR(f[0], base, "4096"); DSR(f[1], base, "5120"); \
                           DSR(f[2], base, "6144"); DSR(f[3], base, "7168"); }
#define READ_B(f, base)  { DSR(f[0], base, "0");    DSR(f[1], base, "1024"); \
                           DSR(f[2], base, "2048"); DSR(f[3], base, "3072"); }

#define MFMA_HALF(i0, af, bf)                                                   \
    _Pragma("unroll")                                                           \
    for (int i_ = 0; i_ < 4; i_++) {                                            \
        bf16x8 a_ = __builtin_bit_cast(bf16x8, af[i_]);                         \
        _Pragma("unroll")                                                       \
        for (int j_ = 0; j_ < 4; j_++)                                          \
            acc[i0 + i_][j_] = __builtin_amdgcn_mfma_f32_16x16x32_bf16(         \
                a_, __builtin_bit_cast(bf16x8, bf[j_]), acc[i0 + i_][j_], 0, 0, 0); \
    }

#define GEMM_ITER(T, BCUR, BNXT)                                                \
  {                                                                             \
    const int T_ = (T);                                                         \
    if (T_ <= NT - 3)      asm volatile("s_waitcnt vmcnt(4)" ::: "memory");     \
    else if (T_ == NT - 2) asm volatile("s_waitcnt vmcnt(0)" ::: "memory");     \
    __builtin_amdgcn_s_barrier();                                               \
    __builtin_amdgcn_sched_barrier(0);                                          \
    if (T_ + 3 < NT) stage(T_ + 3, (T_ + 3) & 3);                               \
    asm volatile("s_waitcnt lgkmcnt(4)" ::: "memory");                          \
    __builtin_amdgcn_sched_barrier(0);                                          \
    __builtin_amdgcn_s_setprio(1);                                              \
    MFMA_HALF(0, af0, BCUR);                                                    \
    __builtin_amdgcn_s_setprio(0);                                              \
    const int tn_ = T_ + 1;                                                     \
    const unsigned aN_ = aLane + (unsigned)((tn_ & 3) * FSLOT_BYTES);           \
    const unsigned bN_ = bLane + (unsigned)((tn_ & 3) * FSLOT_BYTES);           \
    if (tn_ < NT) {                                                             \
      READ_A0(af0, aN_);                                                        \
      READ_B(BNXT, bN_);                                                        \
      asm volatile("s_waitcnt lgkmcnt(8)" ::: "memory");                        \
    } else {                                                                    \
      asm volatile("s_waitcnt lgkmcnt(0)" ::: "memory");                        \
    }                                                                           \
    __builtin_amdgcn_sched_barrier(0);                                          \
    __builtin_amdgcn_s_setprio(1);                                              \
    MFMA_HALF(4, af1, BCUR);                                                    \
    __builtin_amdgcn_s_setprio(0);                                              \
    if (tn_ < NT) { READ_A1(af1, aN_); }                                        \
  }

__global__ __launch_bounds__(512, 2)
void gemm_final(const unsigned short* __restrict__ A,
                const unsigned short* __restrict__ Bt,
                const float* __restrict__ bias,
                float* __restrict__ Cf,
                int M, int K) {
    __shared__ __align__(16) unsigned short As[4 * FSLOT_ELEMS];
    __shared__ __align__(16) unsigned short Bs[4 * FSLOT_ELEMS];

    const int tid  = threadIdx.x;
    const int lane = tid & 63;
    const int wave = tid >> 6;     // 0..7
    const int wr   = wave >> 2;    // 0..1  (128-row M half)
    const int wc   = wave & 3;     // 0..3  (64-col N quarter)
    const int quad  = lane >> 4;
    const int row16 = lane & 15;

    // T1 swizzle (512 blocks, %8==0; measured good in this config)
    const int nwg = (int)(gridDim.x * gridDim.y);
    const int bid = (int)(blockIdx.y * gridDim.x + blockIdx.x);
    const int cpx = nwg >> 3;
    const int swz = (bid & 7) * cpx + (bid >> 3);
    const int bm  = swz % (int)gridDim.x;
    const int bn  = swz / (int)gridDim.x;

    const int m0 = bm * 256;
    const int n0 = bn * 256;

    floatx4 acc[8][4] = {};

    const unsigned short* gA[2];
    const unsigned short* gB[2];
    #pragma unroll
    for (int b = 0; b < 2; b++) {
        int s = b * 512 + tid;
        int r = s >> 2, c = s & 3;
        int cg = c ^ ((r >> 1) & 3);
        gA[b] = A  + (size_t)(m0 + r) * K + cg * 8;
        gB[b] = Bt + (size_t)(n0 + r) * K + cg * 8;
    }

    const unsigned asB = LDS_OFF(As);
    const unsigned bsB = LDS_OFF(Bs);
    const unsigned cP    = (unsigned)(quad ^ ((row16 >> 1) & 3));
    const unsigned aLane = asB + (unsigned)(wr * 8192 + row16 * 64) + cP * 16u;
    const unsigned bLane = bsB + (unsigned)(wc * 4096 + row16 * 64) + cP * 16u;

    auto stage = [&](int tt, int sl) {
        const int koff = tt * FBK;
        #pragma unroll
        for (int b = 0; b < 2; b++) {
            int s = b * 512 + tid;
            async_load16(gA[b] + koff, As + sl * FSLOT_ELEMS + s * 8);
            async_load16(gB[b] + koff, Bs + sl * FSLOT_ELEMS + s * 8);
        }
    };

    const int NT = K / FBK;     // 64
    stage(0, 0); stage(1, 1); stage(2, 2);
    asm volatile("s_waitcnt vmcnt(8)" ::: "memory");
    __builtin_amdgcn_s_barrier();
    __builtin_amdgcn_sched_barrier(0);

    uintx4 af0[4], af1[4], bfE[4], bfO[4];
    READ_A0(af0, aLane);
    READ_B(bfE, bLane);
    READ_A1(af1, aLane);

    for (int t = 0; t < NT; t += 2) {
        GEMM_ITER(t,     bfE, bfO);
        GEMM_ITER(t + 1, bfO, bfE);
    }

    float bcache[4];
    #pragma unroll
    for (int j = 0; j < 4; j++) bcache[j] = bias[n0 + wc * 64 + j * 16 + row16];
    #pragma unroll
    for (int i = 0; i < 8; i++) {
        #pragma unroll
        for (int r = 0; r < 4; r++) {
            int row = m0 + wr * 128 + i * 16 + quad * 4 + r;
            #pragma unroll
            for (int j = 0; j < 4; j++) {
                int col = n0 + wc * 64 + j * 16 + row16;
                Cf[(size_t)row * DMODEL + col] = acc[i][j][r] + bcache[j];
            }
        }
    }
}

// ---------- linear-attention scan (elementwise kv), chunked 3-pass ----------
#define SL    4096
#define SD    2048
#define SH    16
#define CHUNK 64
#define NCH   64   // SL / CHUNK

// Pass A: per-(b,h,chunk) partial sums. lane = tg*16+dg: 4 t-rows in flight,
// 16B/lane loads; summation is order-free so cross-lane combine at the end.
__global__ void scan_partial_kernel(const unsigned short* __restrict__ k,
                                    const unsigned short* __restrict__ v,
                                    float* __restrict__ sumK, float* __restrict__ sumKV) {
    int blk = blockIdx.x;
    int c = blk & (NCH - 1), bh = blk >> 6;
    int b = bh >> 4, h = bh & (SH - 1);
    int lane = threadIdx.x;
    int tg = lane >> 4, dg = lane & 15;
    size_t base = ((size_t)(b * SL + c * CHUNK + tg)) * SD + h * 128 + dg * 8;
    float sk[8] = {0.f, 0.f, 0.f, 0.f, 0.f, 0.f, 0.f, 0.f};
    float skv[8] = {0.f, 0.f, 0.f, 0.f, 0.f, 0.f, 0.f, 0.f};
    for (int it = 0; it < CHUNK / 4; it++) {
        ushort8 kw = *(const ushort8*)(k + base);
        ushort8 vw = *(const ushort8*)(v + base);
        #pragma unroll
        for (int j = 0; j < 8; j++) {
            float kf = bf2f(kw[j]);
            float vf = bf2f(vw[j]);
            sk[j] += kf; skv[j] += kf * vf;
        }
        base += (size_t)4 * SD;
    }
    #pragma unroll
    for (int j = 0; j < 8; j++) {
        sk[j]  += __shfl_xor(sk[j], 16);  sk[j]  += __shfl_xor(sk[j], 32);
        skv[j] += __shfl_xor(skv[j], 16); skv[j] += __shfl_xor(skv[j], 32);
    }
    if (tg == 0) {
        size_t o = ((size_t)bh * NCH + c) * 128 + dg * 8;
        *(float4*)(sumK  + o)     = make_float4(sk[0], sk[1], sk[2], sk[3]);
        *(float4*)(sumK  + o + 4) = make_float4(sk[4], sk[5], sk[6], sk[7]);
        *(float4*)(sumKV + o)     = make_float4(skv[0], skv[1], skv[2], skv[3]);
        *(float4*)(sumKV + o + 4) = make_float4(skv[4], skv[5], skv[6], skv[7]);
    }
}

// Pass B: exclusive scan of chunk sums along chunk axis, per (b,h,d).
// Register-batched: 32 independent coalesced loads in flight, then scan+store.
__global__ __launch_bounds__(64)
void scan_offsets_kernel(const float* __restrict__ sumK, const float* __restrict__ sumKV,
                         float* __restrict__ offK, float* __restrict__ offKV) {
    int blk = blockIdx.x;            // 0..127 = bh*2 + dh
    int bh  = blk >> 1;
    int d   = (blk & 1) * 64 + threadIdx.x;
    float aK = 0.f, aKV = 0.f;
    #pragma unroll 1
    for (int h = 0; h < 2; h++) {
        float vK[32], vKV[32];
        #pragma unroll
        for (int c2 = 0; c2 < 32; c2++) {
            size_t o = ((size_t)bh * NCH + h * 32 + c2) * 128 + d;
            vK[c2] = sumK[o]; vKV[c2] = sumKV[o];
        }
        #pragma unroll
        for (int c2 = 0; c2 < 32; c2++) {
            size_t o = ((size_t)bh * NCH + h * 32 + c2) * 128 + d;
            offK[o]  = aK;  aK  += vK[c2];
            offKV[o] = aKV; aKV += vKV[c2];
        }
    }
}

// Pass C: within-chunk sequential scan. TWO heads per block, 4 chans/lane:
// 8B loads (half the load count per byte), 5-stage reduce over 32-lane halves.
// lane = half*32 + dq; half selects head hp*2+half; dq covers 128 chans (4 each).
__global__ void scan_final_kernel(const unsigned short* __restrict__ q,
                                  const unsigned short* __restrict__ k,
                                  const unsigned short* __restrict__ v,
                                  const float* __restrict__ offK, const float* __restrict__ offKV,
                                  const float* __restrict__ mask,
                                  unsigned short* __restrict__ out) {
    int blk = blockIdx.x;              // 2048 = (b*8+hp)*64 + c
    int c   = blk & (NCH - 1);
    int bhp = blk >> 6;                // 0..31
    int b = bhp >> 3, hp = bhp & 7;
    int lane = threadIdx.x;
    int half = lane >> 5, dq = lane & 31;
    int h  = hp * 2 + half;
    int bh = b * SH + h;

    size_t ob = ((size_t)bh * NCH + c) * 128 + dq * 4;
    float4 kc4 = *(const float4*)(offK  + ob);
    float4 kv4 = *(const float4*)(offKV + ob);
    float kc[4] = {kc4.x, kc4.y, kc4.z, kc4.w};
    float kv[4] = {kv4.x, kv4.y, kv4.z, kv4.w};

    size_t base = ((size_t)(b * SL + c * CHUNK)) * SD + h * 128 + dq * 4;
    const float* mrow = mask + (size_t)b * SL + c * CHUNK;

    for (int s = 0; s < CHUNK / 4; s++) {
        uint2 kw[4], vw[4], qw[4];
        #pragma unroll
        for (int u = 0; u < 4; u++) {
            size_t a = base + (size_t)u * SD;
            kw[u] = *(const uint2*)(k + a);
            vw[u] = *(const uint2*)(v + a);
            qw[u] = *(const uint2*)(q + a);
        }
        float p[4], nn[4][4];
        #pragma unroll
        for (int u = 0; u < 4; u++) {
            float kf[4], vf[4], qf[4];
            kf[0] = bf2f(kw[u].x & 0xffff); kf[1] = bf2f(kw[u].x >> 16);
            kf[2] = bf2f(kw[u].y & 0xffff); kf[3] = bf2f(kw[u].y >> 16);
            vf[0] = bf2f(vw[u].x & 0xffff); vf[1] = bf2f(vw[u].x >> 16);
            vf[2] = bf2f(vw[u].y & 0xffff); vf[3] = bf2f(vw[u].y >> 16);
            qf[0] = bf2f(qw[u].x & 0xffff); qf[1] = bf2f(qw[u].x >> 16);
            qf[2] = bf2f(qw[u].y & 0xffff); qf[3] = bf2f(qw[u].y >> 16);
            float pu = 0.f;
            #pragma unroll
            for (int j = 0; j < 4; j++) {
                kc[j] += kf[j];
                kv[j] += kf[j] * vf[j];
                pu += qf[j] * kc[j];
                nn[u][j] = qf[j] * kv[j];
            }
            p[u] = pu;
        }
        #pragma unroll
        for (int off = 16; off > 0; off >>= 1) {   // reduce within 32-lane half
            #pragma unroll
            for (int u = 0; u < 4; u++) p[u] += __shfl_xor(p[u], off);
        }
        #pragma unroll
        for (int u = 0; u < 4; u++) {
            float z = (p[u] + EPS_F) * mrow[s * 4 + u];
            float inv = 1.0f / z;
            uint2 o2;
            unsigned lo0 = f2bf(nn[u][0] * inv), hi0 = f2bf(nn[u][1] * inv);
            unsigned lo1 = f2bf(nn[u][2] * inv), hi1 = f2bf(nn[u][3] * inv);
            o2.x = lo0 | (hi0 << 16);
            o2.y = lo1 | (hi1 << 16);
            *(uint2*)(out + base + (size_t)u * SD) = o2;
        }
        base += (size_t)4 * SD;
    }
}

// ---------- launcher ----------
extern "C" void kernel_launch(void* const* d_in, const int* in_sizes, int n_in,
                              void* d_out, int out_size, void* d_ws, size_t ws_size,
                              hipStream_t stream) {
    const float* x  = (const float*)d_in[0];
    const float* am = (const float*)d_in[1];
    const float* Wq = (const float*)d_in[2];
    const float* bq = (const float*)d_in[3];
    const float* Wk = (const float*)d_in[4];
    const float* bk = (const float*)d_in[5];
    const float* Wv = (const float*)d_in[6];
    const float* bv = (const float*)d_in[7];
    const float* Wo = (const float*)d_in[8];
    const float* bo = (const float*)d_in[9];
    float* out = (float*)d_out;

    const int Bb = 4, L = 4096, D = 2048;
    const int M = Bb * L;                       // 16384
    const size_t MD = (size_t)M * D;            // 33,554,432

    // workspace carve-up (~310 MB). attn aliases xb (xb dead after QKV GEMM).
    char* w = (char*)d_ws;
    unsigned short* xb    = (unsigned short*)w; w += MD * 2;
    unsigned short* qb    = (unsigned short*)w; w += MD * 2;
    unsigned short* kb    = (unsigned short*)w; w += MD * 2;
    unsigned short* vb    = (unsigned short*)w; w += MD * 2;
    unsigned short* WT    = (unsigned short*)w; w += (size_t)4 * D * D * 2; // [WqT;WkT;WvT;WoT]
    float* sumK  = (float*)w; w += (size_t)64 * NCH * 128 * 4;
    float* sumKV = (float*)w; w += (size_t)64 * NCH * 128 * 4;
    float* offK  = (float*)w; w += (size_t)64 * NCH * 128 * 4;
    float* offKV = (float*)w; w += (size_t)64 * NCH * 128 * 4;
    unsigned short* attnb = xb;                 // alias

    // 1) casts / transposes
    int n8 = (int)(MD / 8);
    cast_x_kernel<<<(n8 + 255) / 256, 256, 0, stream>>>(x, xb, n8);
    dim3 tb(32, 8);
    dim3 tg(D / 32, D / 32, 4);
    transpose_cast_kernel<<<tg, tb, 0, stream>>>(Wq, Wk, Wv, Wo, WT, D);

    // 2) fused QKV projection (N = 3*D), epilogues fused. 128x48 grid, natural order.
    dim3 gq(M / BMT, 3 * D / BNT);
    gemm_qkv<<<gq, 256, 0, stream>>>(xb, WT, bq, bk, bv, am, qb, kb, vb, M, D);

    // 3) chunked linear-attention scan
    scan_partial_kernel<<<64 * NCH, 64, 0, stream>>>(kb, vb, sumK, sumKV);
    scan_offsets_kernel<<<128, 64, 0, stream>>>(sumK, sumKV, offK, offKV);
    scan_final_kernel<<<2048, 64, 0, stream>>>(qb, kb, vb, offK, offKV, am, attnb);

    // 4) output projection -> fp32 d_out. 256^2 ring-4 kernel, grid 64x8 = 512.
    dim3 go(M / 256, D / 256);
    gemm_final<<<go, 512, 0, stream>>>(attnb, WT + (size_t)3 * D * D, bo, out, M, D);
}

// Round 6
// 878.642 us; speedup vs baseline: 1.1125x; 1.0199x over previous
//
#include <hip/hip_runtime.h>
#include <cstdint>
#include <cstddef>

#define EPS_F 1e-6f

// ---------- bf16 helpers ----------
__device__ inline unsigned short f2bf(float f) {
    union { float f; unsigned u; } v; v.f = f;
    unsigned r = v.u + 0x7fffu + ((v.u >> 16) & 1u);   // RNE
    return (unsigned short)(r >> 16);
}
__device__ inline float bf2f(unsigned u16) {           // low 16 bits used
    union { unsigned u; float f; } v; v.u = u16 << 16; return v.f;
}

typedef __attribute__((ext_vector_type(8))) __bf16 bf16x8;
typedef __attribute__((ext_vector_type(8))) short short8;
typedef __attribute__((ext_vector_type(8))) unsigned short ushort8;
typedef __attribute__((ext_vector_type(4))) float floatx4;
typedef __attribute__((ext_vector_type(4))) unsigned uintx4;

__device__ inline void async_load16(const void* g, void* l) {
    __builtin_amdgcn_global_load_lds((const __attribute__((address_space(1))) void*)g,
                                     (__attribute__((address_space(3))) void*)l,
                                     16, 0, 0);
}

#define LDS_OFF(p) ((unsigned)(unsigned long long)(const __attribute__((address_space(3))) void*)(p))

// ---------- cast fp32 -> bf16, 8 elems/thread (16B store) ----------
__global__ void cast_x_kernel(const float* __restrict__ in, unsigned short* __restrict__ out, int n8) {
    int i = blockIdx.x * blockDim.x + threadIdx.x;
    if (i < n8) {
        float4 a = ((const float4*)in)[2 * i];
        float4 b = ((const float4*)in)[2 * i + 1];
        short8 o;
        o[0] = (short)f2bf(a.x); o[1] = (short)f2bf(a.y);
        o[2] = (short)f2bf(a.z); o[3] = (short)f2bf(a.w);
        o[4] = (short)f2bf(b.x); o[5] = (short)f2bf(b.y);
        o[6] = (short)f2bf(b.z); o[7] = (short)f2bf(b.w);
        ((short8*)out)[i] = o;
    }
}

// ---------- transpose + cast 4 weights in one dispatch (blockIdx.z selects) ----------
__global__ void transpose_cast_kernel(const float* __restrict__ W0, const float* __restrict__ W1,
                                      const float* __restrict__ W2, const float* __restrict__ W3,
                                      unsigned short* __restrict__ WtBase, int n) {
    const float* W = (blockIdx.z == 0) ? W0 : (blockIdx.z == 1) ? W1 : (blockIdx.z == 2) ? W2 : W3;
    unsigned short* Wt = WtBase + (size_t)blockIdx.z * n * n;
    __shared__ float tile[32][33];
    int bx = blockIdx.x * 32;
    int by = blockIdx.y * 32;
    int tx = threadIdx.x;        // 0..31
    int ty = threadIdx.y;        // 0..7
    #pragma unroll
    for (int i = 0; i < 32; i += 8)
        tile[ty + i][tx] = W[(size_t)(by + ty + i) * n + bx + tx];
    __syncthreads();
    #pragma unroll
    for (int i = 0; i < 32; i += 8)
        Wt[(size_t)(bx + ty + i) * n + by + tx] = f2bf(tile[tx][ty + i]);
}

// ---------- shared 256x256 / BK=32 ring-4 register-pipelined GEMM machinery --------
#define DMODEL 2048
#define FBK 32
#define FSLOT_ELEMS (256 * FBK)   // 8192 bf16 = 16 KB per slot per matrix
#define FSLOT_BYTES 16384

#define DSR(dst, base, OFF) \
    asm volatile("ds_read_b128 %0, %1 offset:" OFF : "=v"(dst) : "v"(base) : "memory")
#define READ_A0(f, base) { DSR(f[0], base, "0");    DSR(f[1], base, "1024"); \
                           DSR(f[2], base, "2048"); DSR(f[3], base, "3072"); }
#define READ_A1(f, base) { DSR(f[0], base, "4096"); DSR(f[1], base, "5120"); \
                           DSR(f[2], base, "6144"); DSR(f[3], base, "7168"); }
#define READ_B(f, base)  { DSR(f[0], base, "0");    DSR(f[1], base, "1024"); \
                           DSR(f[2], base, "2048"); DSR(f[3], base, "3072"); }

#define MFMA_HALF(i0, af, bf)                                                   \
    _Pragma("unroll")                                                           \
    for (int i_ = 0; i_ < 4; i_++) {                                            \
        bf16x8 a_ = __builtin_bit_cast(bf16x8, af[i_]);                         \
        _Pragma("unroll")                                                       \
        for (int j_ = 0; j_ < 4; j_++)                                          \
            acc[i0 + i_][j_] = __builtin_amdgcn_mfma_f32_16x16x32_bf16(         \
                a_, __builtin_bit_cast(bf16x8, bf[j_]), acc[i0 + i_][j_], 0, 0, 0); \
    }

// Per iteration t (slot = t&3), steady state:
//   vmcnt(4): tile t+1 landed (t+2 in flight) ; barrier ; stage(t+3) into (t-1)&3
//   lgkmcnt(4): af0(t)+bf(t) ready ; 16 MFMA ; issue af0/bf reads of t+1
//   lgkmcnt(8): af1(t) ready       ; 16 MFMA ; issue af1 reads of t+1
#define GEMM_ITER(T, BCUR, BNXT)                                                \
  {                                                                             \
    const int T_ = (T);                                                         \
    if (T_ <= NT - 3)      asm volatile("s_waitcnt vmcnt(4)" ::: "memory");     \
    else if (T_ == NT - 2) asm volatile("s_waitcnt vmcnt(0)" ::: "memory");     \
    __builtin_amdgcn_s_barrier();                                               \
    __builtin_amdgcn_sched_barrier(0);                                          \
    if (T_ + 3 < NT) stage(T_ + 3, (T_ + 3) & 3);                               \
    asm volatile("s_waitcnt lgkmcnt(4)" ::: "memory");                          \
    __builtin_amdgcn_sched_barrier(0);                                          \
    __builtin_amdgcn_s_setprio(1);                                              \
    MFMA_HALF(0, af0, BCUR);                                                    \
    __builtin_amdgcn_s_setprio(0);                                              \
    const int tn_ = T_ + 1;                                                     \
    const unsigned aN_ = aLane + (unsigned)((tn_ & 3) * FSLOT_BYTES);           \
    const unsigned bN_ = bLane + (unsigned)((tn_ & 3) * FSLOT_BYTES);           \
    if (tn_ < NT) {                                                             \
      READ_A0(af0, aN_);                                                        \
      READ_B(BNXT, bN_);                                                        \
      asm volatile("s_waitcnt lgkmcnt(8)" ::: "memory");                        \
    } else {                                                                    \
      asm volatile("s_waitcnt lgkmcnt(0)" ::: "memory");                        \
    }                                                                           \
    __builtin_amdgcn_sched_barrier(0);                                          \
    __builtin_amdgcn_s_setprio(1);                                              \
    MFMA_HALF(4, af1, BCUR);                                                    \
    __builtin_amdgcn_s_setprio(0);                                              \
    if (tn_ < NT) { READ_A1(af1, aN_); }                                        \
  }

// ---------- QKV GEMM: 256x256 ring-4, NATURAL block order --------------------------
// Natural m-fast order: concurrent blocks span all m-panels of ~4 n-panels ->
// A window = all of A, L3-resident, temporally shared by all XCDs (R4 mechanism).
__global__ __launch_bounds__(512, 2)
void gemm_qkv(const unsigned short* __restrict__ A,
              const unsigned short* __restrict__ Bt,
              const float* __restrict__ b0, const float* __restrict__ b1,
              const float* __restrict__ b2,
              const float* __restrict__ mask,
              unsigned short* __restrict__ qo, unsigned short* __restrict__ ko,
              unsigned short* __restrict__ vo,
              int M, int K) {
    __shared__ __align__(16) unsigned short As[4 * FSLOT_ELEMS];
    __shared__ __align__(16) unsigned short Bs[4 * FSLOT_ELEMS];

    const int tid  = threadIdx.x;
    const int lane = tid & 63;
    const int wave = tid >> 6;     // 0..7
    const int wr   = wave >> 2;    // 0..1  (128-row M half)
    const int wc   = wave & 3;     // 0..3  (64-col N quarter)
    const int quad  = lane >> 4;
    const int row16 = lane & 15;

    const int m0    = blockIdx.x * 256;      // natural order (no XCD swizzle)
    const int nglob = blockIdx.y * 256;
    const int mat = nglob >> 11;             // /DMODEL (256 divides 2048: no straddle)
    const int n0  = nglob & (DMODEL - 1);
    const float* bias = (mat == 0) ? b0 : (mat == 1) ? b1 : b2;
    unsigned short* Cb = (mat == 0) ? qo : (mat == 1) ? ko : vo;

    floatx4 acc[8][4] = {};

    const unsigned short* gA[2];
    const unsigned short* gB[2];
    #pragma unroll
    for (int b = 0; b < 2; b++) {
        int s = b * 512 + tid;
        int r = s >> 2, c = s & 3;
        int cg = c ^ ((r >> 1) & 3);
        gA[b] = A  + (size_t)(m0 + r) * K + cg * 8;
        gB[b] = Bt + (size_t)(nglob + r) * K + cg * 8;
    }

    const unsigned asB = LDS_OFF(As);
    const unsigned bsB = LDS_OFF(Bs);
    const unsigned cP    = (unsigned)(quad ^ ((row16 >> 1) & 3));
    const unsigned aLane = asB + (unsigned)(wr * 8192 + row16 * 64) + cP * 16u;
    const unsigned bLane = bsB + (unsigned)(wc * 4096 + row16 * 64) + cP * 16u;

    auto stage = [&](int tt, int sl) {
        const int koff = tt * FBK;
        #pragma unroll
        for (int b = 0; b < 2; b++) {
            int s = b * 512 + tid;
            async_load16(gA[b] + koff, As + sl * FSLOT_ELEMS + s * 8);
            async_load16(gB[b] + koff, Bs + sl * FSLOT_ELEMS + s * 8);
        }
    };

    const int NT = K / FBK;     // 64
    stage(0, 0); stage(1, 1); stage(2, 2);
    asm volatile("s_waitcnt vmcnt(8)" ::: "memory");
    __builtin_amdgcn_s_barrier();
    __builtin_amdgcn_sched_barrier(0);

    uintx4 af0[4], af1[4], bfE[4], bfO[4];
    READ_A0(af0, aLane);
    READ_B(bfE, bLane);
    READ_A1(af1, aLane);

    for (int t = 0; t < NT; t += 2) {
        GEMM_ITER(t,     bfE, bfO);
        GEMM_ITER(t + 1, bfO, bfE);
    }

    // epilogue: D row = wr*128 + i*16 + quad*4 + r, col = wc*64 + j*16 + row16
    float bcache[4];
    #pragma unroll
    for (int j = 0; j < 4; j++) bcache[j] = bias[n0 + wc * 64 + j * 16 + row16];
    #pragma unroll
    for (int i = 0; i < 8; i++) {
        #pragma unroll
        for (int r = 0; r < 4; r++) {
            int row = m0 + wr * 128 + i * 16 + quad * 4 + r;
            float mr = (mat >= 1) ? mask[row] : 1.0f;
            #pragma unroll
            for (int j = 0; j < 4; j++) {
                int col = n0 + wc * 64 + j * 16 + row16;
                float v = acc[i][j][r] + bcache[j];
                if (mat <= 1) v = (v > 0.f) ? (v + 1.f) : __expf(v);  // elu+1
                v *= mr;
                Cb[(size_t)row * DMODEL + col] = f2bf(v);
            }
        }
    }
}

// ---------- Final GEMM: 256x256 ring-4, XCD-swizzled (512 blocks: 1 n-panel/XCD) ---
__global__ __launch_bounds__(512, 2)
void gemm_final(const unsigned short* __restrict__ A,
                const unsigned short* __restrict__ Bt,
                const float* __restrict__ bias,
                float* __restrict__ Cf,
                int M, int K) {
    __shared__ __align__(16) unsigned short As[4 * FSLOT_ELEMS];
    __shared__ __align__(16) unsigned short Bs[4 * FSLOT_ELEMS];

    const int tid  = threadIdx.x;
    const int lane = tid & 63;
    const int wave = tid >> 6;     // 0..7
    const int wr   = wave >> 2;    // 0..1
    const int wc   = wave & 3;     // 0..3
    const int quad  = lane >> 4;
    const int row16 = lane & 15;

    const int nwg = (int)(gridDim.x * gridDim.y);
    const int bid = (int)(blockIdx.y * gridDim.x + blockIdx.x);
    const int cpx = nwg >> 3;
    const int swz = (bid & 7) * cpx + (bid >> 3);
    const int bm  = swz % (int)gridDim.x;
    const int bn  = swz / (int)gridDim.x;

    const int m0 = bm * 256;
    const int n0 = bn * 256;

    floatx4 acc[8][4] = {};

    const unsigned short* gA[2];
    const unsigned short* gB[2];
    #pragma unroll
    for (int b = 0; b < 2; b++) {
        int s = b * 512 + tid;
        int r = s >> 2, c = s & 3;
        int cg = c ^ ((r >> 1) & 3);
        gA[b] = A  + (size_t)(m0 + r) * K + cg * 8;
        gB[b] = Bt + (size_t)(n0 + r) * K + cg * 8;
    }

    const unsigned asB = LDS_OFF(As);
    const unsigned bsB = LDS_OFF(Bs);
    const unsigned cP    = (unsigned)(quad ^ ((row16 >> 1) & 3));
    const unsigned aLane = asB + (unsigned)(wr * 8192 + row16 * 64) + cP * 16u;
    const unsigned bLane = bsB + (unsigned)(wc * 4096 + row16 * 64) + cP * 16u;

    auto stage = [&](int tt, int sl) {
        const int koff = tt * FBK;
        #pragma unroll
        for (int b = 0; b < 2; b++) {
            int s = b * 512 + tid;
            async_load16(gA[b] + koff, As + sl * FSLOT_ELEMS + s * 8);
            async_load16(gB[b] + koff, Bs + sl * FSLOT_ELEMS + s * 8);
        }
    };

    const int NT = K / FBK;     // 64
    stage(0, 0); stage(1, 1); stage(2, 2);
    asm volatile("s_waitcnt vmcnt(8)" ::: "memory");
    __builtin_amdgcn_s_barrier();
    __builtin_amdgcn_sched_barrier(0);

    uintx4 af0[4], af1[4], bfE[4], bfO[4];
    READ_A0(af0, aLane);
    READ_B(bfE, bLane);
    READ_A1(af1, aLane);

    for (int t = 0; t < NT; t += 2) {
        GEMM_ITER(t,     bfE, bfO);
        GEMM_ITER(t + 1, bfO, bfE);
    }

    float bcache[4];
    #pragma unroll
    for (int j = 0; j < 4; j++) bcache[j] = bias[n0 + wc * 64 + j * 16 + row16];
    #pragma unroll
    for (int i = 0; i < 8; i++) {
        #pragma unroll
        for (int r = 0; r < 4; r++) {
            int row = m0 + wr * 128 + i * 16 + quad * 4 + r;
            #pragma unroll
            for (int j = 0; j < 4; j++) {
                int col = n0 + wc * 64 + j * 16 + row16;
                Cf[(size_t)row * DMODEL + col] = acc[i][j][r] + bcache[j];
            }
        }
    }
}

// ---------- linear-attention scan (elementwise kv), chunked 3-pass ----------
#define SL    4096
#define SD    2048
#define SH    16
#define CHUNK 64
#define NCH   64   // SL / CHUNK

// Pass A: per-(b,h,chunk) partial sums.
__global__ void scan_partial_kernel(const unsigned short* __restrict__ k,
                                    const unsigned short* __restrict__ v,
                                    float* __restrict__ sumK, float* __restrict__ sumKV) {
    int blk = blockIdx.x;
    int c = blk & (NCH - 1), bh = blk >> 6;
    int b = bh >> 4, h = bh & (SH - 1);
    int lane = threadIdx.x;
    int tg = lane >> 4, dg = lane & 15;
    size_t base = ((size_t)(b * SL + c * CHUNK + tg)) * SD + h * 128 + dg * 8;
    float sk[8] = {0.f, 0.f, 0.f, 0.f, 0.f, 0.f, 0.f, 0.f};
    float skv[8] = {0.f, 0.f, 0.f, 0.f, 0.f, 0.f, 0.f, 0.f};
    for (int it = 0; it < CHUNK / 4; it++) {
        ushort8 kw = *(const ushort8*)(k + base);
        ushort8 vw = *(const ushort8*)(v + base);
        #pragma unroll
        for (int j = 0; j < 8; j++) {
            float kf = bf2f(kw[j]);
            float vf = bf2f(vw[j]);
            sk[j] += kf; skv[j] += kf * vf;
        }
        base += (size_t)4 * SD;
    }
    #pragma unroll
    for (int j = 0; j < 8; j++) {
        sk[j]  += __shfl_xor(sk[j], 16);  sk[j]  += __shfl_xor(sk[j], 32);
        skv[j] += __shfl_xor(skv[j], 16); skv[j] += __shfl_xor(skv[j], 32);
    }
    if (tg == 0) {
        size_t o = ((size_t)bh * NCH + c) * 128 + dg * 8;
        *(float4*)(sumK  + o)     = make_float4(sk[0], sk[1], sk[2], sk[3]);
        *(float4*)(sumK  + o + 4) = make_float4(sk[4], sk[5], sk[6], sk[7]);
        *(float4*)(sumKV + o)     = make_float4(skv[0], skv[1], skv[2], skv[3]);
        *(float4*)(sumKV + o + 4) = make_float4(skv[4], skv[5], skv[6], skv[7]);
    }
}

// Pass B: exclusive scan of chunk sums along chunk axis, per (b,h,d).
__global__ __launch_bounds__(64)
void scan_offsets_kernel(const float* __restrict__ sumK, const float* __restrict__ sumKV,
                         float* __restrict__ offK, float* __restrict__ offKV) {
    int blk = blockIdx.x;            // 0..127 = bh*2 + dh
    int bh  = blk >> 1;
    int d   = (blk & 1) * 64 + threadIdx.x;
    float aK = 0.f, aKV = 0.f;
    #pragma unroll 1
    for (int h = 0; h < 2; h++) {
        float vK[32], vKV[32];
        #pragma unroll
        for (int c2 = 0; c2 < 32; c2++) {
            size_t o = ((size_t)bh * NCH + h * 32 + c2) * 128 + d;
            vK[c2] = sumK[o]; vKV[c2] = sumKV[o];
        }
        #pragma unroll
        for (int c2 = 0; c2 < 32; c2++) {
            size_t o = ((size_t)bh * NCH + h * 32 + c2) * 128 + d;
            offK[o]  = aK;  aK  += vK[c2];
            offKV[o] = aKV; aKV += vKV[c2];
        }
    }
}

// Pass C: within-chunk sequential scan. TWO heads per block, 4 chans/lane.
__global__ void scan_final_kernel(const unsigned short* __restrict__ q,
                                  const unsigned short* __restrict__ k,
                                  const unsigned short* __restrict__ v,
                                  const float* __restrict__ offK, const float* __restrict__ offKV,
                                  const float* __restrict__ mask,
                                  unsigned short* __restrict__ out) {
    int blk = blockIdx.x;              // 2048 = (b*8+hp)*64 + c
    int c   = blk & (NCH - 1);
    int bhp = blk >> 6;                // 0..31
    int b = bhp >> 3, hp = bhp & 7;
    int lane = threadIdx.x;
    int half = lane >> 5, dq = lane & 31;
    int h  = hp * 2 + half;
    int bh = b * SH + h;

    size_t ob = ((size_t)bh * NCH + c) * 128 + dq * 4;
    float4 kc4 = *(const float4*)(offK  + ob);
    float4 kv4 = *(const float4*)(offKV + ob);
    float kc[4] = {kc4.x, kc4.y, kc4.z, kc4.w};
    float kv[4] = {kv4.x, kv4.y, kv4.z, kv4.w};

    size_t base = ((size_t)(b * SL + c * CHUNK)) * SD + h * 128 + dq * 4;
    const float* mrow = mask + (size_t)b * SL + c * CHUNK;

    for (int s = 0; s < CHUNK / 4; s++) {
        uint2 kw[4], vw[4], qw[4];
        #pragma unroll
        for (int u = 0; u < 4; u++) {
            size_t a = base + (size_t)u * SD;
            kw[u] = *(const uint2*)(k + a);
            vw[u] = *(const uint2*)(v + a);
            qw[u] = *(const uint2*)(q + a);
        }
        float p[4], nn[4][4];
        #pragma unroll
        for (int u = 0; u < 4; u++) {
            float kf[4], vf[4], qf[4];
            kf[0] = bf2f(kw[u].x & 0xffff); kf[1] = bf2f(kw[u].x >> 16);
            kf[2] = bf2f(kw[u].y & 0xffff); kf[3] = bf2f(kw[u].y >> 16);
            vf[0] = bf2f(vw[u].x & 0xffff); vf[1] = bf2f(vw[u].x >> 16);
            vf[2] = bf2f(vw[u].y & 0xffff); vf[3] = bf2f(vw[u].y >> 16);
            qf[0] = bf2f(qw[u].x & 0xffff); qf[1] = bf2f(qw[u].x >> 16);
            qf[2] = bf2f(qw[u].y & 0xffff); qf[3] = bf2f(qw[u].y >> 16);
            float pu = 0.f;
            #pragma unroll
            for (int j = 0; j < 4; j++) {
                kc[j] += kf[j];
                kv[j] += kf[j] * vf[j];
                pu += qf[j] * kc[j];
                nn[u][j] = qf[j] * kv[j];
            }
            p[u] = pu;
        }
        #pragma unroll
        for (int off = 16; off > 0; off >>= 1) {   // reduce within 32-lane half
            #pragma unroll
            for (int u = 0; u < 4; u++) p[u] += __shfl_xor(p[u], off);
        }
        #pragma unroll
        for (int u = 0; u < 4; u++) {
            float z = (p[u] + EPS_F) * mrow[s * 4 + u];
            float inv = 1.0f / z;
            uint2 o2;
            unsigned lo0 = f2bf(nn[u][0] * inv), hi0 = f2bf(nn[u][1] * inv);
            unsigned lo1 = f2bf(nn[u][2] * inv), hi1 = f2bf(nn[u][3] * inv);
            o2.x = lo0 | (hi0 << 16);
            o2.y = lo1 | (hi1 << 16);
            *(uint2*)(out + base + (size_t)u * SD) = o2;
        }
        base += (size_t)4 * SD;
    }
}

// ---------- launcher ----------
extern "C" void kernel_launch(void* const* d_in, const int* in_sizes, int n_in,
                              void* d_out, int out_size, void* d_ws, size_t ws_size,
                              hipStream_t stream) {
    const float* x  = (const float*)d_in[0];
    const float* am = (const float*)d_in[1];
    const float* Wq = (const float*)d_in[2];
    const float* bq = (const float*)d_in[3];
    const float* Wk = (const float*)d_in[4];
    const float* bk = (const float*)d_in[5];
    const float* Wv = (const float*)d_in[6];
    const float* bv = (const float*)d_in[7];
    const float* Wo = (const float*)d_in[8];
    const float* bo = (const float*)d_in[9];
    float* out = (float*)d_out;

    const int Bb = 4, L = 4096, D = 2048;
    const int M = Bb * L;                       // 16384
    const size_t MD = (size_t)M * D;            // 33,554,432

    // workspace carve-up (~310 MB). attn aliases xb (xb dead after QKV GEMM).
    char* w = (char*)d_ws;
    unsigned short* xb    = (unsigned short*)w; w += MD * 2;
    unsigned short* qb    = (unsigned short*)w; w += MD * 2;
    unsigned short* kb    = (unsigned short*)w; w += MD * 2;
    unsigned short* vb    = (unsigned short*)w; w += MD * 2;
    unsigned short* WT    = (unsigned short*)w; w += (size_t)4 * D * D * 2; // [WqT;WkT;WvT;WoT]
    float* sumK  = (float*)w; w += (size_t)64 * NCH * 128 * 4;
    float* sumKV = (float*)w; w += (size_t)64 * NCH * 128 * 4;
    float* offK  = (float*)w; w += (size_t)64 * NCH * 128 * 4;
    float* offKV = (float*)w; w += (size_t)64 * NCH * 128 * 4;
    unsigned short* attnb = xb;                 // alias

    // 1) casts / transposes
    int n8 = (int)(MD / 8);
    cast_x_kernel<<<(n8 + 255) / 256, 256, 0, stream>>>(x, xb, n8);
    dim3 tb(32, 8);
    dim3 tg(D / 32, D / 32, 4);
    transpose_cast_kernel<<<tg, tb, 0, stream>>>(Wq, Wk, Wv, Wo, WT, D);

    // 2) fused QKV projection (N = 3*D). 256^2 ring-4, natural order. grid 64x24.
    dim3 gq(M / 256, 3 * D / 256);
    gemm_qkv<<<gq, 512, 0, stream>>>(xb, WT, bq, bk, bv, am, qb, kb, vb, M, D);

    // 3) chunked linear-attention scan
    scan_partial_kernel<<<64 * NCH, 64, 0, stream>>>(kb, vb, sumK, sumKV);
    scan_offsets_kernel<<<128, 64, 0, stream>>>(sumK, sumKV, offK, offKV);
    scan_final_kernel<<<2048, 64, 0, stream>>>(qb, kb, vb, offK, offKV, am, attnb);

    // 4) output projection -> fp32 d_out. 256^2 ring-4, swizzled. grid 64x8 = 512.
    dim3 go(M / 256, D / 256);
    gemm_final<<<go, 512, 0, stream>>>(attnb, WT + (size_t)3 * D * D, bo, out, M, D);
}